// Round 1
// 162.406 us; speedup vs baseline: 1.1250x; 1.1250x over previous
//
#include <hip/hip_runtime.h>
#include <hip/hip_bf16.h>

// MultiScaleAttention: B=1,S=2048,D=1024,H=16,DH=64,WIN=128,DIL=4.
// ESTABLISHED: inputs fp32, output fp32, ws 256 MiB.
// Round-14: UNIFIED ATTENTION. All three scales share s(q,k) and static-max
// softmax => p identical across modes. Iterate keys residue-major (group
// rho = keys with seq%4==rho, 8 tiles each); within-tile key placement chosen
// so PV ks2-phase = 32-key half. Then:
//   - global  = full 32-tile accumulation (unchanged math)
//   - dilated = accumulator delta across group rho==r (slot r holds row
//               residue r) -- zero extra MFMA
//   - local   = delta across ONE PV phase of tile (t&7)==g>>2, phase (g>>1)&1,
//               in each group (16 extra MFMA/block via mfma(a,b,0))
// o written ONCE (no RMW chain); 3 attn launches -> 1; Q/K/V staged once.
// vT layout + gemm0 epilogue updated: V[seq] at G = 512*(seq&3)
//   + 64*(j>>6) + 32*(k64>>5) + 4*(k64&7) + ((k64>>3)&3), j=seq>>2, k64=j&63.
// Everything else byte-identical to round-13 (182.7us measured).

typedef __attribute__((ext_vector_type(8))) short s8v;   // 8 bf16
typedef __attribute__((ext_vector_type(4))) float f4v;   // 4 fp32

#define QSCALE 0.18033688011112042f   // 0.125 * log2(e)

__device__ __forceinline__ short f2bf(float f) {
  union { float f; unsigned u; } x; x.f = f;
  unsigned r = (x.u + 0x7FFF + ((x.u >> 16) & 1)) >> 16;   // RNE
  return (short)r;
}
__device__ __forceinline__ float bf2f(short s) {
  union { unsigned u; float f; } x; x.u = ((unsigned)(unsigned short)s) << 16;
  return x.f;
}
__device__ __forceinline__ f4v mfma16(s8v a, s8v b, f4v c) {
  return __builtin_amdgcn_mfma_f32_16x16x32_bf16(a, b, c, 0, 0, 0);
}
__device__ __forceinline__ void load_lds16(const void* g, void* l) {
  __builtin_amdgcn_global_load_lds(
      (const __attribute__((address_space(1))) unsigned int*)g,
      (__attribute__((address_space(3))) unsigned int*)l, 16, 0, 0);
}
__device__ __forceinline__ float exp2f_fast(float x) {
  return __builtin_amdgcn_exp2f(x);     // v_exp_f32: D = 2^S0
}

__global__ __launch_bounds__(256)
void fill_const_kernel(float* __restrict__ out, int n, float v) {
  int i = blockIdx.x * 256 + threadIdx.x;
  if (i < n) out[i] = v;
}

__global__ __launch_bounds__(256)
void cast_f32_bf16(const float* __restrict__ src, short* __restrict__ dst, int n) {
  int i = (blockIdx.x * 256 + threadIdx.x) * 4;
  if (i < n) {
    float4 v = *reinterpret_cast<const float4*>(&src[i]);
    union { short s[4]; int2 p; } u;
    u.s[0] = f2bf(v.x); u.s[1] = f2bf(v.y); u.s[2] = f2bf(v.z); u.s[3] = f2bf(v.w);
    *reinterpret_cast<int2*>(&dst[i]) = u.p;
  }
}

// ---------- transpose+convert: src fp32 [K][N] -> dst bf16 [N][K] ----------
__global__ __launch_bounds__(256)
void transpose_conv(const float* __restrict__ src, short* __restrict__ dst,
                    int K, int N) {
  __shared__ float T[64][69];
  const int n0 = blockIdx.x * 64, k0 = blockIdx.y * 64;
  const int t = threadIdx.x;
  for (int jb = t; jb < 1024; jb += 256) {
    int r = jb >> 4, c4 = (jb & 15) * 4;
    float4 v = *reinterpret_cast<const float4*>(&src[(size_t)(k0 + r) * N + n0 + c4]);
    T[c4 + 0][r] = v.x; T[c4 + 1][r] = v.y; T[c4 + 2][r] = v.z; T[c4 + 3][r] = v.w;
  }
  __syncthreads();
  for (int jb = t; jb < 512; jb += 256) {
    int n = jb >> 3, k8 = (jb & 7) * 8;
    union { short s[8]; int4 v; } p;
#pragma unroll
    for (int i = 0; i < 8; ++i) p.s[i] = f2bf(T[n][k8 + i]);
    *reinterpret_cast<int4*>(&dst[(size_t)(n0 + n) * K + k0 + k8]) = p.v;
  }
}

// ---------- MFMA GEMM, 64xNT tile, BK=32, C = A * Bt^T ----------
// COUT 0 (g1): C split -> qb (pre-scaled by QSCALE) / kb row-major bf16,
//              V stored to vT in residue-major permuted layout (see header).
// COUT 1 (g2): C fp32 = acc/3 -> co.
template <int COUT, bool AF32, int NT>
__global__ __launch_bounds__(256)
void gemm_tile(const void* __restrict__ Av, const short* __restrict__ Bt,
               short* __restrict__ qb, short* __restrict__ kb,
               short* __restrict__ vT, float* __restrict__ co,
               int K, int N) {
  __shared__ __align__(16) short As[64 * 32];
  __shared__ __align__(16) short Bs[NT * 32];
  const int tid = threadIdx.x, wave = tid >> 6;
  const int li = tid & 63;
  const int row0 = blockIdx.y * 64, col0 = blockIdx.x * NT;
  const int lr = li & 15, quad = li >> 4, lk = quad * 8;
  constexpr int NTW = NT / 64;          // n-16-tiles per wave (2 or 1)

  f4v acc[4][NTW];
#pragma unroll
  for (int i = 0; i < 4; ++i)
#pragma unroll
    for (int j = 0; j < NTW; ++j) acc[i][j] = (f4v){0.f, 0.f, 0.f, 0.f};

  for (int k0 = 0; k0 < K; k0 += 32) {
    __syncthreads();
#pragma unroll
    for (int u = 0; u < NTW; ++u)
      load_lds16(Bt + (size_t)(col0 + u * 64 + (tid >> 2)) * K + k0 + (tid & 3) * 8,
                 &Bs[u * 2048 + wave * 512]);
    if (AF32) {
      const float* A = (const float*)Av;
#pragma unroll
      for (int c = 0; c < 2; ++c) {
        int j = c * 256 + tid;           // 512 float4 chunks
        int r = j >> 3, c4 = (j & 7) * 4;
        float4 v = *reinterpret_cast<const float4*>(&A[(size_t)(row0 + r) * K + k0 + c4]);
        union { short s[4]; int2 v2; } p;
        p.s[0] = f2bf(v.x); p.s[1] = f2bf(v.y); p.s[2] = f2bf(v.z); p.s[3] = f2bf(v.w);
        *reinterpret_cast<int2*>(&As[r * 32 + c4]) = p.v2;
      }
    } else {
      load_lds16((const short*)Av + (size_t)(row0 + (tid >> 2)) * K + k0 + (tid & 3) * 8,
                 &As[wave * 512]);
    }
    __syncthreads();

    s8v af[4], bfr[NTW];
#pragma unroll
    for (int mt = 0; mt < 4; ++mt)
      af[mt] = *reinterpret_cast<const s8v*>(&As[(mt * 16 + lr) * 32 + lk]);
#pragma unroll
    for (int u = 0; u < NTW; ++u)
      bfr[u] = *reinterpret_cast<const s8v*>(&Bs[(wave * (NT / 4) + u * 16 + lr) * 32 + lk]);
#pragma unroll
    for (int mt = 0; mt < 4; ++mt)
#pragma unroll
      for (int u = 0; u < NTW; ++u)
        acc[mt][u] = mfma16(af[mt], bfr[u], acc[mt][u]);
  }

  // epilogue: C/D layout col=lane&15, row=quad*4+reg
#pragma unroll
  for (int mt = 0; mt < 4; ++mt) {
#pragma unroll
    for (int u = 0; u < NTW; ++u) {
      int gcol = col0 + wave * (NT / 4) + u * 16 + lr;
      int grow0 = row0 + mt * 16 + quad * 4;
      if (COUT == 0) {
        if (gcol >= 2048) {              // vT, residue-major permuted layout
          int d = gcol - 2048;
          int j = grow0 >> 2;            // group position; residue = reg idx r
          int k64 = j & 63;
          int gb = ((j >> 6) << 6) + ((k64 >> 5) << 5) +
                   ((k64 & 7) << 2) + ((k64 >> 3) & 3);
          size_t base = (size_t)d * 2048 + gb;
#pragma unroll
          for (int r = 0; r < 4; ++r)
            vT[base + (r << 9)] = f2bf(acc[mt][u][r]);
        } else {
          short* dst = (gcol < 1024) ? qb : kb;
          float sc = (gcol < 1024) ? QSCALE : 1.0f;
          int c = gcol & 1023;
#pragma unroll
          for (int r = 0; r < 4; ++r)
            dst[(size_t)(grow0 + r) * 1024 + c] = f2bf(acc[mt][u][r] * sc);
        }
      } else {
#pragma unroll
        for (int r = 0; r < 4; ++r)
          co[(size_t)(grow0 + r) * N + gcol] = acc[mt][u][r] * (1.0f / 3.0f);
      }
    }
  }
}

// ---------- unified flash attention: global+local+dilated in one pass ------
// 512 blocks: h=b&15, g=b>>4 (q rows g*64..+63). 32 key tiles, residue-major:
// tile t: group rho=t>>3 (keys seq%4==rho), in-group tile t&7; within-tile key
// placement k64(n) = 32*((n&15)>>3) + 8*(n>>4) + (n&7) so PV phase ks2 covers
// key half ks2. Dilated = group-delta on slot r==rho; local = phase-delta on
// tile (t&7)==(g>>2), phase (g>>1)&1. Static-max softmax, dbuf K/V, register
// prefetch, ONE barrier/tile.
__global__ __launch_bounds__(256, 2)
void attn_unified(const short* __restrict__ qb, const short* __restrict__ kb,
                  const short* __restrict__ vT, short* __restrict__ o) {
  __shared__ __align__(16) short Qs[64][72];
  __shared__ __align__(16) short Ks[2][64][72];
  __shared__ __align__(16) short Vt[2][64][72];   // [d][kappa], permuted layout
  __shared__ __align__(16) short Pls[64][72];

  const int tid = threadIdx.x;
  const int wave = tid >> 6, li = tid & 63;
  const int b = blockIdx.x, h = b & 15, g = b >> 4;
  const int qcol = h * 64;
  const int lr = li & 15, quad = li >> 4, lk = quad * 8;
  const int wt2 = g >> 2;            // in-group tile holding the local window
  const int wH  = (g >> 1) & 1;      // which 32-key half of that tile
  const bool wlane = ((lr >> 3) == wH);

  // Q staging (qb pre-scaled by QSCALE at g1); rows g*64..+63 natural
  for (int jb = tid; jb < 512; jb += 256) {
    int r = jb >> 3, c8 = (jb & 7) * 8;
    *reinterpret_cast<int4*>(&Qs[r][c8]) =
        *reinterpret_cast<const int4*>(&qb[(size_t)(g * 64 + r) * 1024 + qcol + c8]);
  }
  // stage tile 0 into buffer 0 (rho=0, in-group tile 0)
#pragma unroll
  for (int c = 0; c < 2; ++c) {
    int j = c * 256 + tid;
    int r = j >> 3, c8 = (j & 7) * 8;
    int k64 = ((r & 8) << 2) + ((r >> 4) << 3) + (r & 7);
    *reinterpret_cast<int4*>(&Ks[0][r][c8]) =
        *reinterpret_cast<const int4*>(&kb[(size_t)(k64 << 2) * 1024 + qcol + c8]);
    *reinterpret_cast<int4*>(&Vt[0][r][c8]) =
        *reinterpret_cast<const int4*>(&vT[(size_t)(h * 64 + r) * 2048 + c8]);
  }
  __syncthreads();

  float l_r[4]   = {0.f, 0.f, 0.f, 0.f};
  float l_loc[4] = {0.f, 0.f, 0.f, 0.f};
  float l_dil[4] = {0.f, 0.f, 0.f, 0.f};
  float lsnap[4];
  f4v oacc[4], o_loc[4], o_dil[4], snapd[4];
#pragma unroll
  for (int i = 0; i < 4; ++i) {
    oacc[i]  = (f4v){0.f, 0.f, 0.f, 0.f};
    o_loc[i] = (f4v){0.f, 0.f, 0.f, 0.f};
    o_dil[i] = (f4v){0.f, 0.f, 0.f, 0.f};
  }

  for (int t = 0; t < 32; ++t) {
    const int cur = t & 1, nxt = cur ^ 1;
    const bool pf = (t + 1 < 32);
    const bool wtile = ((t & 7) == wt2);

    // group start: snapshot for the dilated delta
    if ((t & 7) == 0) {
#pragma unroll
      for (int i = 0; i < 4; ++i) { snapd[i] = oacc[i]; lsnap[i] = l_r[i]; }
    }

    // prefetch tile t+1 into registers (overlaps compute below)
    int4 kpre[2], vpre[2];
    if (pf) {
#pragma unroll
      for (int c = 0; c < 2; ++c) {
        int j = c * 256 + tid;
        int r = j >> 3, c8 = (j & 7) * 8;
        int k64 = ((r & 8) << 2) + ((r >> 4) << 3) + (r & 7);
        int ks = ((((t + 1) & 7) << 6) + k64) * 4 + ((t + 1) >> 3);
        kpre[c] = *reinterpret_cast<const int4*>(&kb[(size_t)ks * 1024 + qcol + c8]);
        vpre[c] = *reinterpret_cast<const int4*>(
            &vT[(size_t)(h * 64 + r) * 2048 + (t + 1) * 64 + c8]);
      }
    }

    // S = Q K^T (wave owns rows wave*16..+15); qb pre-scaled -> log2 domain
    f4v s4[4];
#pragma unroll
    for (int i = 0; i < 4; ++i) s4[i] = (f4v){0.f, 0.f, 0.f, 0.f};
#pragma unroll
    for (int ks2 = 0; ks2 < 2; ++ks2) {
      s8v aq = *reinterpret_cast<const s8v*>(&Qs[wave * 16 + lr][ks2 * 32 + lk]);
#pragma unroll
      for (int nt = 0; nt < 4; ++nt) {
        s8v bk = *reinterpret_cast<const s8v*>(&Ks[cur][nt * 16 + lr][ks2 * 32 + lk]);
        s4[nt] = mfma16(aq, bk, s4[nt]);
      }
    }

    // static-max softmax: p = exp2(s), per-lane l partials, packed P store.
    // l_loc: window columns have (lr>>3)==wH on the window tile.
#pragma unroll
    for (int r = 0; r < 4; ++r) {
      float p0 = exp2f_fast(s4[0][r]), p1 = exp2f_fast(s4[1][r]),
            p2 = exp2f_fast(s4[2][r]), p3 = exp2f_fast(s4[3][r]);
      float ps = (p0 + p1) + (p2 + p3);
      l_r[r] += ps;
      l_loc[r] += (wtile && wlane) ? ps : 0.f;
      union { short s[4]; int2 v; } pk;
      pk.s[0] = f2bf(p0); pk.s[1] = f2bf(p1); pk.s[2] = f2bf(p2); pk.s[3] = f2bf(p3);
      *reinterpret_cast<int2*>(&Pls[wave * 16 + quad * 4 + r][4 * lr]) = pk.v;
    }

    // O += P V  (P rows wave-local; kappa order matches Vt layout).
    // On the window tile, phase wH also feeds o_loc via mfma(a,b,0).
#pragma unroll
    for (int ks2 = 0; ks2 < 2; ++ks2) {
      s8v ap = *reinterpret_cast<const s8v*>(&Pls[wave * 16 + lr][ks2 * 32 + lk]);
      bool sh = wtile && (wH == ks2);
      if (sh) {
#pragma unroll
        for (int nt = 0; nt < 4; ++nt) {
          s8v bv = *reinterpret_cast<const s8v*>(&Vt[cur][nt * 16 + lr][ks2 * 32 + lk]);
          f4v dd = mfma16(ap, bv, (f4v){0.f, 0.f, 0.f, 0.f});
          oacc[nt] += dd;
          o_loc[nt] += dd;
        }
      } else {
#pragma unroll
        for (int nt = 0; nt < 4; ++nt) {
          s8v bv = *reinterpret_cast<const s8v*>(&Vt[cur][nt * 16 + lr][ks2 * 32 + lk]);
          oacc[nt] = mfma16(ap, bv, oacc[nt]);
        }
      }
    }

    // group end: dilated delta lands in slot r==rho only
    if ((t & 7) == 7) {
      const int rho = t >> 3;
#pragma unroll
      for (int i = 0; i < 4; ++i) {
        float m = (i == rho) ? 1.f : 0.f;
        l_dil[i] += m * (l_r[i] - lsnap[i]);
#pragma unroll
        for (int nt = 0; nt < 4; ++nt)
          o_dil[nt][i] += m * (oacc[nt][i] - snapd[nt][i]);
      }
    }

    // write prefetched tile into the other buffer; single barrier per tile
    if (pf) {
#pragma unroll
      for (int c = 0; c < 2; ++c) {
        int j = c * 256 + tid;
        int r = j >> 3, c8 = (j & 7) * 8;
        *reinterpret_cast<int4*>(&Ks[nxt][r][c8]) = kpre[c];
        *reinterpret_cast<int4*>(&Vt[nxt][r][c8]) = vpre[c];
      }
    }
    __syncthreads();
  }

  // epilogue: reduce the three l's over the 16 lanes of each quad, combine
#pragma unroll
  for (int r = 0; r < 4; ++r) {
    float lg = l_r[r], ll = l_loc[r], ld = l_dil[r];
    lg += __shfl_xor(lg, 1, 16);  ll += __shfl_xor(ll, 1, 16);  ld += __shfl_xor(ld, 1, 16);
    lg += __shfl_xor(lg, 2, 16);  ll += __shfl_xor(ll, 2, 16);  ld += __shfl_xor(ld, 2, 16);
    lg += __shfl_xor(lg, 4, 16);  ll += __shfl_xor(ll, 4, 16);  ld += __shfl_xor(ld, 4, 16);
    lg += __shfl_xor(lg, 8, 16);  ll += __shfl_xor(ll, 8, 16);  ld += __shfl_xor(ld, 8, 16);
    float ig = 1.0f / lg, il = 1.0f / ll, id = 1.0f / ld;
    int rowt = wave * 16 + quad * 4 + r;
    int qs = g * 64 + rowt;
#pragma unroll
    for (int nt = 0; nt < 4; ++nt) {
      size_t idx = (size_t)qs * 1024 + qcol + nt * 16 + lr;
      o[idx] = f2bf(oacc[nt][r] * ig + o_loc[nt][r] * il + o_dil[nt][r] * id);
    }
  }
}

extern "C" void kernel_launch(void* const* d_in, const int* in_sizes, int n_in,
                              void* d_out, int out_size, void* d_ws, size_t ws_size,
                              hipStream_t stream) {
  float* out = (float*)d_out;
  const int nfill = (out_size + 255) / 256;
  if (n_in != 3) { fill_const_kernel<<<nfill, 256, 0, stream>>>(out, out_size, 0.5f); return; }
  int ix = -1, iq = -1, io = -1;
  for (int i = 0; i < 3; ++i) {
    if      (in_sizes[i] == 2097152) ix = i;
    else if (in_sizes[i] == 3145728) iq = i;
    else if (in_sizes[i] == 1048576) io = i;
  }
  if (ix < 0 || iq < 0 || io < 0) { fill_const_kernel<<<nfill, 256, 0, stream>>>(out, out_size, 0.3f); return; }
  const float* x     = (const float*)d_in[ix];
  const float* w_qkv = (const float*)d_in[iq];
  const float* w_out = (const float*)d_in[io];

  char* ws = (char*)d_ws;
  const size_t MB = 1048576;
  const size_t needX = 22 * MB;
  const size_t needY = 20 * MB;

  if (ws_size >= needX) {
    short* qb     = (short*)(ws);
    short* kb     = (short*)(ws + 4 * MB);
    short* vT     = (short*)(ws + 8 * MB);
    short* w_qkvT = (short*)(ws + 12 * MB);
    short* xb     = (short*)(ws + 18 * MB);
    short* o      = (short*)(ws + 12 * MB);   // over dead w_qkvT after g1
    short* w_outT = (short*)(ws + 16 * MB);   // over dead w_qkvT after g1
    cast_f32_bf16<<<2048, 256, 0, stream>>>(x, xb, 2097152);
    transpose_conv<<<dim3(48, 16), 256, 0, stream>>>(w_qkv, w_qkvT, 1024, 3072);
    gemm_tile<0, false, 128><<<dim3(24, 32), 256, 0, stream>>>(xb, w_qkvT, qb, kb, vT, nullptr, 1024, 3072);
    transpose_conv<<<dim3(16, 16), 256, 0, stream>>>(w_out, w_outT, 1024, 1024);
    attn_unified<<<512, 256, 0, stream>>>(qb, kb, vT, o);
    gemm_tile<1, false, 64><<<dim3(16, 32), 256, 0, stream>>>(o, w_outT, nullptr, nullptr, nullptr, out, 1024, 1024);
  } else if (ws_size >= needY) {
    short* w_outT = (short*)(ws);
    short* qb     = (short*)(ws + 2 * MB);
    short* kb     = (short*)(ws + 6 * MB);
    short* vT     = (short*)(ws + 10 * MB);
    short* w_qkvT = (short*)(ws + 14 * MB);
    short* o      = (short*)(ws + 14 * MB);   // over dead w_qkvT after g1
    transpose_conv<<<dim3(48, 16), 256, 0, stream>>>(w_qkv, w_qkvT, 1024, 3072);
    transpose_conv<<<dim3(16, 16), 256, 0, stream>>>(w_out, w_outT, 1024, 1024);
    gemm_tile<0, true, 128><<<dim3(24, 32), 256, 0, stream>>>(x, w_qkvT, qb, kb, vT, nullptr, 1024, 3072);
    attn_unified<<<512, 256, 0, stream>>>(qb, kb, vT, o);
    gemm_tile<1, false, 64><<<dim3(16, 32), 256, 0, stream>>>(o, w_outT, nullptr, nullptr, nullptr, out, 1024, 1024);
  } else {
    fill_const_kernel<<<nfill, 256, 0, stream>>>(out, out_size, 0.2f);
  }
}